// Round 5
// baseline (275.793 us; speedup 1.0000x reference)
//
#include <hip/hip_runtime.h>
#include <math.h>

// Problem constants (fixed by the reference's shapes)
#define NROWS   131072      // 32*64*64 spatial positions
#define DFEAT   64          // feature dim (C)
#define KHALF   512         // rows per embedding table
#define HW      4096        // 64*64
#define CHW     262144      // 64*4096
#define NQOUT   8388608     // 32*64*64*64 quantized elements
#define MAIN_BLOCKS 1024    // NROWS / 128

typedef __attribute__((ext_vector_type(8))) short   bf16x8;
typedef __attribute__((ext_vector_type(4))) float   f32x4;

__device__ __forceinline__ unsigned short f2bf(float f) {
    unsigned int u = __float_as_uint(f);
    u += 0x7FFFu + ((u >> 16) & 1u);          // round-to-nearest-even
    return (unsigned short)(u >> 16);
}
__device__ __forceinline__ float bf2f(unsigned short h) {
    return __uint_as_float(((unsigned int)h) << 16);
}

// ---------------------------------------------------------------------------
// Kernel 0: prep — pack B fragments (hi/lo bf16), ncn = -0.5||c||^2, zero ws.
// fragbuf[tile(64)][frag(4)][lane(64)][j(8)]:
//   frag 0: hi k=0..31   frag 1: hi k=32..63   frag 2: lo k=0..31   frag 3: lo k=32..63
//   lane L holds code (tile*16 + (L&15)), feats kb..kb+7, kb=(f&1)*32+(L>>4)*8
// ---------------------------------------------------------------------------
__global__ void vq_prep(const float* __restrict__ e0, const float* __restrict__ e1,
                        const float* __restrict__ e2, const int* __restrict__ idxp,
                        unsigned short* __restrict__ fragbuf, float* __restrict__ ncn,
                        int* __restrict__ hist, float* __restrict__ loss_acc,
                        int* __restrict__ done) {
    const int tau = blockIdx.x * 256 + threadIdx.x;   // 64 blocks * 256 = 16384
    const int idx = idxp[0];
    const float* sel = (idx == 2) ? e2 : e1;

    // --- pack one 8-elem fragment slice ---
    {
        int tile = tau >> 8;
        int rem  = tau & 255;
        int f    = rem >> 6;
        int L    = rem & 63;
        int code = tile * 16 + (L & 15);
        int kb   = (f & 1) * 32 + (L >> 4) * 8;
        int lo_f = f >> 1;
        const float* src = (code < KHALF) ? (e0 + (size_t)code * DFEAT)
                                          : (sel + (size_t)(code - KHALF) * DFEAT);
        unsigned short* dst = fragbuf + (size_t)tau * 8;
#pragma unroll
        for (int j = 0; j < 8; ++j) {
            float v = src[kb + j];
            unsigned short hb = f2bf(v);
            dst[j] = lo_f ? f2bf(v - bf2f(hb)) : hb;
        }
    }

    // --- ncn = -0.5*||c||^2 (exact fp32) ---
    if (tau < 1024) {
        const float* row = (tau < KHALF) ? (e0 + (size_t)tau * DFEAT)
                                         : (sel + (size_t)(tau - KHALF) * DFEAT);
        float s = 0.f;
#pragma unroll
        for (int c = 0; c < DFEAT; ++c) s = fmaf(row[c], row[c], s);
        ncn[tau] = -0.5f * s;
    }

    // --- zero hist / loss / done ---
    if (blockIdx.x == 0) {
#pragma unroll
        for (int i = 0; i < 4; ++i) hist[threadIdx.x * 4 + i] = 0;
        if (threadIdx.x == 0) { loss_acc[0] = 0.f; done[0] = 0; }
    }
}

// ---------------------------------------------------------------------------
// Kernel 1: main VQ. 1024 blocks x 256 threads (4 waves) -> 4 waves/SIMD.
// 32 rows per wave (2 MFMA row-tiles). Per tile: 3 independent MFMA chains
// of depth 2 per row-tile (hi*hi, hi*lo, lo*hi) summed in VALU — max chain
// depth 2 to avoid per-tile MFMA-latency drain. B prefetched per-wave in
// registers (no barriers in K-loop). Last block finalizes loss+perplexity.
// ---------------------------------------------------------------------------
__global__ __launch_bounds__(256, 4) void vq_main(
        const float* __restrict__ x,
        const float* __restrict__ e0, const float* __restrict__ e1,
        const float* __restrict__ e2, const int* __restrict__ idxp,
        const float* __restrict__ ncn_g, const unsigned short* __restrict__ fragbuf,
        float* __restrict__ out, float* __restrict__ loss_acc,
        int* __restrict__ hist, int* __restrict__ done) {
    __shared__ float ncn_s[1024];
    __shared__ float xsq_s[128];
    __shared__ float sc_s[128];
    __shared__ int   bk_s[128];
    __shared__ float pf[4];
    __shared__ int   lastflag;

    const int t = threadIdx.x;
    const int w = t >> 6;          // wave in block
    const int L = t & 63;          // lane
    const int q = L >> 4;          // quad
    const int m = L & 15;

    const int rowbase = blockIdx.x * 128;   // 128 | 4096: never straddles an image
    const int n  = rowbase >> 12;
    const int s0 = rowbase & 4095;

    const int idx = idxp[0];
    const float* sel = (idx == 2) ? e2 : e1;
    const int ntiles = (idx == 0) ? 32 : 64;

    // ---- stage -0.5||c||^2 into LDS ----
#pragma unroll
    for (int i = 0; i < 4; ++i) ncn_s[i * 256 + t] = ncn_g[i * 256 + t];

    // ---- A fragments: 2 row-tiles of 16 rows, hi/lo bf16 + ||x||^2 ----
    bf16x8 ahi[2][2], alo[2][2];
    const float* xb = x + (size_t)n * CHW + (s0 + w * 32);
#pragma unroll
    for (int rt = 0; rt < 2; ++rt) {
        const float* xr = xb + rt * 16 + m;
        float xs = 0.f;
#pragma unroll
        for (int h = 0; h < 2; ++h) {
#pragma unroll
            for (int j = 0; j < 8; ++j) {
                int c = h * 32 + q * 8 + j;
                float v = xr[(size_t)c * HW];
                xs = fmaf(v, v, xs);
                unsigned short hb = f2bf(v);
                unsigned short lb = f2bf(v - bf2f(hb));
                ahi[rt][h][j] = (short)hb;
                alo[rt][h][j] = (short)lb;
            }
        }
        xs += __shfl_xor(xs, 16, 64);
        xs += __shfl_xor(xs, 32, 64);
        if (q == 0) xsq_s[w * 32 + rt * 16 + m] = xs;
    }
    __syncthreads();   // ncn_s ready

    // ---- stream 64 code tiles; score = x.c - 0.5||c||^2, argMAX ----
    const bf16x8* fb = (const bf16x8*)fragbuf;
    float best[8];
    int   bidx[8];
#pragma unroll
    for (int i = 0; i < 8; ++i) { best[i] = -3.4e38f; bidx[i] = 0; }

    bf16x8 bh0 = fb[0 * 64 + L];
    bf16x8 bh1 = fb[1 * 64 + L];
    bf16x8 bl0 = fb[2 * 64 + L];
    bf16x8 bl1 = fb[3 * 64 + L];

    for (int tt = 0; tt < ntiles; ++tt) {
        const int tn = (tt + 1 < ntiles) ? tt + 1 : tt;
        bf16x8 nh0 = fb[(tn * 4 + 0) * 64 + L];
        bf16x8 nh1 = fb[(tn * 4 + 1) * 64 + L];
        bf16x8 nl0 = fb[(tn * 4 + 2) * 64 + L];
        bf16x8 nl1 = fb[(tn * 4 + 3) * 64 + L];
        const int kt = tt * 16 + m;      // this lane's candidate code id (col = m)
        const float nc = ncn_s[kt];
#pragma unroll
        for (int rt = 0; rt < 2; ++rt) {
            // 3 independent chains of depth 2 (no 6-deep acc serialization)
            f32x4 p = {nc, nc, nc, nc};
            f32x4 qa = {0.f, 0.f, 0.f, 0.f};
            f32x4 ra = {0.f, 0.f, 0.f, 0.f};
            p  = __builtin_amdgcn_mfma_f32_16x16x32_bf16(ahi[rt][0], bh0, p,  0, 0, 0);
            qa = __builtin_amdgcn_mfma_f32_16x16x32_bf16(ahi[rt][0], bl0, qa, 0, 0, 0);
            ra = __builtin_amdgcn_mfma_f32_16x16x32_bf16(alo[rt][0], bh0, ra, 0, 0, 0);
            p  = __builtin_amdgcn_mfma_f32_16x16x32_bf16(ahi[rt][1], bh1, p,  0, 0, 0);
            qa = __builtin_amdgcn_mfma_f32_16x16x32_bf16(ahi[rt][1], bl1, qa, 0, 0, 0);
            ra = __builtin_amdgcn_mfma_f32_16x16x32_bf16(alo[rt][1], bh1, ra, 0, 0, 0);
#pragma unroll
            for (int r = 0; r < 4; ++r) {
                float s = p[r] + qa[r] + ra[r];
                if (s > best[rt * 4 + r]) { best[rt * 4 + r] = s; bidx[rt * 4 + r] = kt; }
            }
        }
        bh0 = nh0; bh1 = nh1; bl0 = nl0; bl1 = nl1;
    }

    // ---- reduce argmax across the 16 cols (lane bits 0-3) ----
#pragma unroll
    for (int i = 0; i < 8; ++i) {
        float b = best[i]; int k = bidx[i];
#pragma unroll
        for (int off = 1; off < 16; off <<= 1) {
            float ob = __shfl_xor(b, off, 64);
            int   ok = __shfl_xor(k, off, 64);
            if (ob > b || (ob == b && ok < k)) { b = ob; k = ok; }
        }
        if (m == 0) {   // D row = q*4 + r within tile rt = i>>2
            int row = w * 32 + (i >> 2) * 16 + q * 4 + (i & 3);
            sc_s[row] = b; bk_s[row] = k;
        }
    }
    __syncthreads();

    // ---- epilogue: 2 threads per row (row = t&127, channel half = t>>7) ----
    {
        const int r  = t & 127;
        const int h2 = t >> 7;
        const int k  = bk_s[r];
        float l = (h2 == 0) ? (xsq_s[r] - 2.f * sc_s[r]) : 0.f;  // ||x-q||^2
#pragma unroll
        for (int off = 32; off > 0; off >>= 1) l += __shfl_down(l, off, 64);
        if (L == 0 && w < 2) atomicAdd(loss_acc, l);
        if (h2 == 0) atomicAdd(&hist[k], 1);

        const float* cp = (k < KHALF) ? (e0 + (size_t)k * DFEAT)
                                      : (sel + (size_t)(k - KHALF) * DFEAT);
        const float4* cp4 = (const float4*)(cp + h2 * 32);
        float* op = out + (size_t)n * CHW + (size_t)h2 * 32 * HW + (s0 + r);
#pragma unroll
        for (int c4 = 0; c4 < 8; ++c4) {
            float4 v = cp4[c4];
            op[(size_t)(4 * c4 + 0) * HW] = v.x;
            op[(size_t)(4 * c4 + 1) * HW] = v.y;
            op[(size_t)(4 * c4 + 2) * HW] = v.z;
            op[(size_t)(4 * c4 + 3) * HW] = v.w;
        }
    }

    // ---- last-block finalize: loss scalar + perplexity ----
    __threadfence();
    __syncthreads();
    if (t == 0) lastflag = (atomicAdd(done, 1) == MAIN_BLOCKS - 1);
    __syncthreads();
    if (!lastflag) return;

    float term = 0.f;
#pragma unroll
    for (int i = 0; i < 4; ++i) {
        int h = atomicAdd(&hist[t * 4 + i], 0);        // device-coherent read
        float p = (float)h / (float)NROWS;
        term += p * logf(p + 1e-10f);                  // p==0 -> exactly 0
    }
#pragma unroll
    for (int off = 32; off > 0; off >>= 1) term += __shfl_down(term, off, 64);
    if (L == 0) pf[w] = term;
    __syncthreads();
    if (t == 0) {
        float s = pf[0] + pf[1] + pf[2] + pf[3];
        float lv = atomicAdd(loss_acc, 0.f);           // device-coherent read
        out[NQOUT]     = 1.25f * (lv / (float)NQOUT);  // q_loss + 0.25*e_loss
        out[NQOUT + 1] = expf(-s);                     // perplexity
    }
}

// ---------------------------------------------------------------------------
extern "C" void kernel_launch(void* const* d_in, const int* in_sizes, int n_in,
                              void* d_out, int out_size, void* d_ws, size_t ws_size,
                              hipStream_t stream) {
    const float* x  = (const float*)d_in[0];
    const float* e0 = (const float*)d_in[1];
    const float* e1 = (const float*)d_in[2];
    const float* e2 = (const float*)d_in[3];
    const int* idxp = (const int*)d_in[4];
    float* out = (float*)d_out;

    // ws layout (floats): [0] loss | [2] done(int) | [256..1280) hist
    //                     [2048..3072) ncn | [4096..) fragbuf (256 KB)
    float* wsf      = (float*)d_ws;
    float* loss_acc = wsf;
    int*   done     = (int*)(wsf + 2);
    int*   hist     = (int*)(wsf + 256);
    float* ncn      = wsf + 2048;
    unsigned short* fragbuf = (unsigned short*)(wsf + 4096);

    vq_prep<<<64, 256, 0, stream>>>(e0, e1, e2, idxp, fragbuf, ncn, hist, loss_acc, done);
    vq_main<<<MAIN_BLOCKS, 256, 0, stream>>>(x, e0, e1, e2, idxp, ncn, fragbuf,
                                             out, loss_acc, hist, done);
}

// Round 6
// 218.683 us; speedup vs baseline: 1.2612x; 1.2612x over previous
//
#include <hip/hip_runtime.h>
#include <math.h>

// Problem constants (fixed by the reference's shapes)
#define NROWS   131072      // 32*64*64 spatial positions
#define DFEAT   64          // feature dim (C)
#define KHALF   512         // rows per embedding table
#define HW      4096        // 64*64
#define CHW     262144      // 64*4096
#define NQOUT   8388608     // 32*64*64*64 quantized elements
#define MAIN_BLOCKS 512     // NROWS / 256

typedef __attribute__((ext_vector_type(8))) short   bf16x8;
typedef __attribute__((ext_vector_type(4))) float   f32x4;

__device__ __forceinline__ unsigned short f2bf(float f) {
    unsigned int u = __float_as_uint(f);
    u += 0x7FFFu + ((u >> 16) & 1u);          // round-to-nearest-even
    return (unsigned short)(u >> 16);
}
__device__ __forceinline__ float bf2f(unsigned short h) {
    return __uint_as_float(((unsigned int)h) << 16);
}

// ---------------------------------------------------------------------------
// Kernel 0: prep — pack B fragments (hi/lo bf16), ncn = -0.5||c||^2, zero ws.
// fragbuf[tile(64)][frag(4)][lane(64)][j(8)]:
//   frag 0: hi k=0..31   frag 1: hi k=32..63   frag 2: lo k=0..31   frag 3: lo k=32..63
//   lane L holds code (tile*16 + (L&15)), feats kb..kb+7, kb=(f&1)*32+(L>>4)*8
// ---------------------------------------------------------------------------
__global__ void vq_prep(const float* __restrict__ e0, const float* __restrict__ e1,
                        const float* __restrict__ e2, const int* __restrict__ idxp,
                        unsigned short* __restrict__ fragbuf, float* __restrict__ ncn,
                        int* __restrict__ hist, float* __restrict__ loss_acc,
                        int* __restrict__ done) {
    const int tau = blockIdx.x * 256 + threadIdx.x;   // 64 blocks * 256 = 16384
    const int idx = idxp[0];
    const float* sel = (idx == 2) ? e2 : e1;

    // --- pack one 8-elem fragment slice ---
    {
        int tile = tau >> 8;
        int rem  = tau & 255;
        int f    = rem >> 6;
        int L    = rem & 63;
        int code = tile * 16 + (L & 15);
        int kb   = (f & 1) * 32 + (L >> 4) * 8;
        int lo_f = f >> 1;
        const float* src = (code < KHALF) ? (e0 + (size_t)code * DFEAT)
                                          : (sel + (size_t)(code - KHALF) * DFEAT);
        unsigned short* dst = fragbuf + (size_t)tau * 8;
#pragma unroll
        for (int j = 0; j < 8; ++j) {
            float v = src[kb + j];
            unsigned short hb = f2bf(v);
            dst[j] = lo_f ? f2bf(v - bf2f(hb)) : hb;
        }
    }

    // --- ncn = -0.5*||c||^2 (exact fp32) ---
    if (tau < 1024) {
        const float* row = (tau < KHALF) ? (e0 + (size_t)tau * DFEAT)
                                         : (sel + (size_t)(tau - KHALF) * DFEAT);
        float s = 0.f;
#pragma unroll
        for (int c = 0; c < DFEAT; ++c) s = fmaf(row[c], row[c], s);
        ncn[tau] = -0.5f * s;
    }

    // --- zero hist / loss / done ---
    if (blockIdx.x == 0) {
#pragma unroll
        for (int i = 0; i < 4; ++i) hist[threadIdx.x * 4 + i] = 0;
        if (threadIdx.x == 0) { loss_acc[0] = 0.f; done[0] = 0; }
    }
}

// ---------------------------------------------------------------------------
// Kernel 1: main VQ. 512 blocks x 256 threads (4 waves); 64 rows per wave
// (4 MFMA row-tiles of 16). B register-prefetched (no K-loop barriers).
// Accumulators double-buffered: tile t's 24 MFMAs issue while tile t-1's
// scores are consumed (argmax) — AGPR reads land ~1 tile (~500 cyc) after
// their producing MFMA, killing the result-read hazard stall.
// ---------------------------------------------------------------------------
__global__ __launch_bounds__(256, 2) void vq_main(
        const float* __restrict__ x,
        const float* __restrict__ e0, const float* __restrict__ e1,
        const float* __restrict__ e2, const int* __restrict__ idxp,
        const float* __restrict__ ncn_g, const unsigned short* __restrict__ fragbuf,
        float* __restrict__ out, float* __restrict__ loss_acc,
        int* __restrict__ hist, int* __restrict__ done) {
    __shared__ float ncn_s[1024];
    __shared__ float xsq_s[256];
    __shared__ float sc_s[256];
    __shared__ int   bk_s[256];
    __shared__ float pf[4];
    __shared__ int   lastflag;

    const int t = threadIdx.x;
    const int w = t >> 6;          // wave in block
    const int L = t & 63;          // lane
    const int q = L >> 4;          // quad
    const int m = L & 15;

    const int rowbase = blockIdx.x * 256;   // 256 | 4096: never straddles an image
    const int n  = rowbase >> 12;
    const int s0 = rowbase & 4095;

    const int idx = idxp[0];
    const float* sel = (idx == 2) ? e2 : e1;
    const int ntiles = (idx == 0) ? 32 : 64;

    // ---- stage -0.5||c||^2 into LDS ----
#pragma unroll
    for (int i = 0; i < 4; ++i) ncn_s[i * 256 + t] = ncn_g[i * 256 + t];

    // ---- A fragments: 4 row-tiles of 16 rows, hi/lo bf16 + ||x||^2 ----
    bf16x8 ahi[4][2], alo[4][2];
    const float* xb = x + (size_t)n * CHW + (s0 + w * 64);
#pragma unroll
    for (int rt = 0; rt < 4; ++rt) {
        const float* xr = xb + rt * 16 + m;
        float xs = 0.f;
#pragma unroll
        for (int h = 0; h < 2; ++h) {
#pragma unroll
            for (int j = 0; j < 8; ++j) {
                int c = h * 32 + q * 8 + j;
                float v = xr[(size_t)c * HW];
                xs = fmaf(v, v, xs);
                unsigned short hb = f2bf(v);
                unsigned short lb = f2bf(v - bf2f(hb));
                ahi[rt][h][j] = (short)hb;
                alo[rt][h][j] = (short)lb;
            }
        }
        xs += __shfl_xor(xs, 16, 64);
        xs += __shfl_xor(xs, 32, 64);
        if (q == 0) xsq_s[w * 64 + rt * 16 + m] = xs;
    }
    __syncthreads();   // ncn_s ready

    // ---- K-loop: software-pipelined issue/consume over 64 code tiles ----
    const bf16x8* fb = (const bf16x8*)fragbuf;
    float best[16];
    int   bidx[16];
#pragma unroll
    for (int i = 0; i < 16; ++i) { best[i] = -3.4e38f; bidx[i] = 0; }

    f32x4 accA[4], accB[4];
    bf16x8 ch0, ch1, cl0, cl1, nh0, nh1, nl0, nl1;

#define LOAD_B(tile) do { \
        nh0 = fb[((tile) * 4 + 0) * 64 + L]; \
        nh1 = fb[((tile) * 4 + 1) * 64 + L]; \
        nl0 = fb[((tile) * 4 + 2) * 64 + L]; \
        nl1 = fb[((tile) * 4 + 3) * 64 + L]; } while (0)
#define SWAP_B() do { ch0 = nh0; ch1 = nh1; cl0 = nl0; cl1 = nl1; } while (0)
#define ISSUE(ACC, TILE) do { \
        const float nc_ = ncn_s[(TILE) * 16 + m]; \
        _Pragma("unroll") \
        for (int rt_ = 0; rt_ < 4; ++rt_) { \
            f32x4 a_ = {nc_, nc_, nc_, nc_}; \
            a_ = __builtin_amdgcn_mfma_f32_16x16x32_bf16(ahi[rt_][0], ch0, a_, 0, 0, 0); \
            a_ = __builtin_amdgcn_mfma_f32_16x16x32_bf16(ahi[rt_][1], ch1, a_, 0, 0, 0); \
            a_ = __builtin_amdgcn_mfma_f32_16x16x32_bf16(ahi[rt_][0], cl0, a_, 0, 0, 0); \
            a_ = __builtin_amdgcn_mfma_f32_16x16x32_bf16(ahi[rt_][1], cl1, a_, 0, 0, 0); \
            a_ = __builtin_amdgcn_mfma_f32_16x16x32_bf16(alo[rt_][0], ch0, a_, 0, 0, 0); \
            a_ = __builtin_amdgcn_mfma_f32_16x16x32_bf16(alo[rt_][1], ch1, a_, 0, 0, 0); \
            (ACC)[rt_] = a_; } } while (0)
#define CONSUME(ACC, TILE) do { \
        const int kt_ = (TILE) * 16 + m; \
        _Pragma("unroll") \
        for (int i_ = 0; i_ < 16; ++i_) { \
            float s_ = (ACC)[i_ >> 2][i_ & 3]; \
            if (s_ > best[i_]) { best[i_] = s_; bidx[i_] = kt_; } } } while (0)

    // prologue: tile 0 into accA
    LOAD_B(0); SWAP_B();
    LOAD_B(1);
    ISSUE(accA, 0);
    SWAP_B();

    for (int tt = 1; tt + 1 < ntiles; tt += 2) {
        LOAD_B(tt + 1);
        ISSUE(accB, tt);
        CONSUME(accA, tt - 1);
        SWAP_B();
        const int tp = (tt + 2 < ntiles) ? tt + 2 : ntiles - 1;
        LOAD_B(tp);
        ISSUE(accA, tt + 1);
        CONSUME(accB, tt);
        SWAP_B();
    }
    // Bcur = tile ntiles-1; issued 0..ntiles-2; consumed 0..ntiles-3
    ISSUE(accB, ntiles - 1);
    CONSUME(accA, ntiles - 2);
    CONSUME(accB, ntiles - 1);

    // ---- reduce argmax across the 16 cols (lane bits 0-3) ----
#pragma unroll
    for (int i = 0; i < 16; ++i) {
        float b = best[i]; int k = bidx[i];
#pragma unroll
        for (int off = 1; off < 16; off <<= 1) {
            float ob = __shfl_xor(b, off, 64);
            int   ok = __shfl_xor(k, off, 64);
            if (ob > b || (ob == b && ok < k)) { b = ob; k = ok; }
        }
        if (m == 0) {   // D row = q*4 + r within tile rt = i>>2
            int row = w * 64 + (i >> 2) * 16 + q * 4 + (i & 3);
            sc_s[row] = b; bk_s[row] = k;
        }
    }
    __syncthreads();

    // ---- epilogue: one thread per row ----
    {
        const int k = bk_s[t];
        float l = xsq_s[t] - 2.f * sc_s[t];    // ||x||^2 - 2x.c + ||c||^2
#pragma unroll
        for (int off = 32; off > 0; off >>= 1) l += __shfl_down(l, off, 64);
        if (L == 0) atomicAdd(loss_acc, l);
        atomicAdd(&hist[k], 1);

        const float* cp = (k < KHALF) ? (e0 + (size_t)k * DFEAT)
                                      : (sel + (size_t)(k - KHALF) * DFEAT);
        const float4* cp4 = (const float4*)cp;
        float* op = out + (size_t)n * CHW + (s0 + t);
#pragma unroll
        for (int c4 = 0; c4 < 16; ++c4) {
            float4 v = cp4[c4];
            op[(size_t)(4 * c4 + 0) * HW] = v.x;
            op[(size_t)(4 * c4 + 1) * HW] = v.y;
            op[(size_t)(4 * c4 + 2) * HW] = v.z;
            op[(size_t)(4 * c4 + 3) * HW] = v.w;
        }
    }

    // ---- last-block finalize: loss scalar + perplexity ----
    __threadfence();
    __syncthreads();
    if (t == 0) lastflag = (atomicAdd(done, 1) == MAIN_BLOCKS - 1);
    __syncthreads();
    if (!lastflag) return;

    float term = 0.f;
#pragma unroll
    for (int i = 0; i < 4; ++i) {
        int h = atomicAdd(&hist[t * 4 + i], 0);        // device-coherent read
        float p = (float)h / (float)NROWS;
        term += p * logf(p + 1e-10f);                  // p==0 -> exactly 0
    }
#pragma unroll
    for (int off = 32; off > 0; off >>= 1) term += __shfl_down(term, off, 64);
    if (L == 0) pf[w] = term;
    __syncthreads();
    if (t == 0) {
        float s = pf[0] + pf[1] + pf[2] + pf[3];
        float lv = atomicAdd(loss_acc, 0.f);           // device-coherent read
        out[NQOUT]     = 1.25f * (lv / (float)NQOUT);  // q_loss + 0.25*e_loss
        out[NQOUT + 1] = expf(-s);                     // perplexity
    }
}

// ---------------------------------------------------------------------------
extern "C" void kernel_launch(void* const* d_in, const int* in_sizes, int n_in,
                              void* d_out, int out_size, void* d_ws, size_t ws_size,
                              hipStream_t stream) {
    const float* x  = (const float*)d_in[0];
    const float* e0 = (const float*)d_in[1];
    const float* e1 = (const float*)d_in[2];
    const float* e2 = (const float*)d_in[3];
    const int* idxp = (const int*)d_in[4];
    float* out = (float*)d_out;

    // ws layout (floats): [0] loss | [2] done(int) | [256..1280) hist
    //                     [2048..3072) ncn | [4096..) fragbuf (256 KB)
    float* wsf      = (float*)d_ws;
    float* loss_acc = wsf;
    int*   done     = (int*)(wsf + 2);
    int*   hist     = (int*)(wsf + 256);
    float* ncn      = wsf + 2048;
    unsigned short* fragbuf = (unsigned short*)(wsf + 4096);

    vq_prep<<<64, 256, 0, stream>>>(e0, e1, e2, idxp, fragbuf, ncn, hist, loss_acc, done);
    vq_main<<<MAIN_BLOCKS, 256, 0, stream>>>(x, e0, e1, e2, idxp, ncn, fragbuf,
                                             out, loss_acc, hist, done);
}